// Round 6
// baseline (1976.699 us; speedup 1.0000x reference)
//
#include <hip/hip_runtime.h>
#include <hip/hip_bf16.h>

#define DEMB 64
typedef unsigned short u16;

__device__ __forceinline__ float bf2f(u16 u) {
    union { unsigned int i; float f; } c; c.i = ((unsigned int)u) << 16; return c.f;
}
__device__ __forceinline__ u16 f2bf(float f) {
    union { float f; unsigned int i; } c; c.f = f;
    unsigned int r = c.i + 0x7FFF + ((c.i >> 16) & 1);
    return (u16)(r >> 16);
}
__device__ __forceinline__ float lo16(unsigned int w) {
    union { unsigned int i; float f; } c; c.i = w << 16; return c.f;
}
__device__ __forceinline__ float hi16(unsigned int w) {
    union { unsigned int i; float f; } c; c.i = w & 0xFFFF0000u; return c.f;
}

// odd 7th-order minimax tanh on [-1.02, 1.02], abs err <= ~3e-4 (inputs are
// l2-normalized so |a| <= 1 + bf16 rounding). 5 VALU ops, no transcendental.
__device__ __forceinline__ float ptanh5(float a) {
    float a2 = a * a;
    float t = fmaf(a2, -0.030095f, 0.124066f);
    t = fmaf(a2, t, -0.332377f);
    t = fmaf(a2, t, 1.0f);
    return a * t;
}

__global__ void init_A_kernel(float4* __restrict__ A, int E) {
    int e = blockIdx.x * blockDim.x + threadIdx.x;
    if (e < E) A[e] = make_float4(1.f, 1.f, 1.f, 1.f);
}

__global__ void concat_copy_kernel(const float* __restrict__ u, const float* __restrict__ it,
                                   float* __restrict__ x, float* __restrict__ acc,
                                   int nu_elems, int total) {
    int i = blockIdx.x * blockDim.x + threadIdx.x;
    if (i >= total) return;
    float v = (i < nu_elems) ? u[i] : it[i - nu_elems];
    x[i] = v;
    acc[i] = v;
}

// ---------------- bucket-partitioned CSR build (by h, bucket = h>>8) --------
__global__ void bcount_kernel(const int* __restrict__ h, int* __restrict__ bcnt, int E) {
    int e = blockIdx.x * blockDim.x + threadIdx.x;
    if (e < E) atomicAdd(&bcnt[((unsigned)h[e]) >> 8], 1);
}

// single block, NB <= 1024 (N <= 262144)
__global__ void bscan_kernel(const int* __restrict__ bcnt, int* __restrict__ bbase,
                             int* __restrict__ off, int NB, int N, int E) {
    __shared__ int s[1024];
    int tid = threadIdx.x;
    int v = (tid < NB) ? bcnt[tid] : 0;
    s[tid] = v;
    __syncthreads();
    for (int o = 1; o < 1024; o <<= 1) {
        int a = (tid >= o) ? s[tid - o] : 0;
        __syncthreads();
        s[tid] += a;
        __syncthreads();
    }
    if (tid < NB) bbase[tid] = s[tid] - v;
    if (tid == 0) { bbase[NB] = E; off[N] = E; }
}

__global__ void bscatter_kernel(const int* __restrict__ h, const int* __restrict__ t,
                                int* __restrict__ bcur, uint2* __restrict__ stg, int E) {
    int e = blockIdx.x * blockDim.x + threadIdx.x;
    if (e >= E) return;
    unsigned hh = (unsigned)h[e];
    int pos = atomicAdd(&bcur[hh >> 8], 1);
    stg[pos] = make_uint2(hh, (unsigned)t[e]);
}

// one block per bucket: per-node count + scan in LDS, write off + csr_t
// (csr_t writes land in one contiguous ~13KB region -> no write amplification)
__global__ void bfinalize_kernel(const uint2* __restrict__ stg, const int* __restrict__ bbase,
                                 int* __restrict__ off, int* __restrict__ csr_t, int N) {
    __shared__ int cnt[256];
    __shared__ int scn[256];
    int b = blockIdx.x, tid = threadIdx.x;
    int ebeg = bbase[b], eend = bbase[b + 1];
    cnt[tid] = 0;
    __syncthreads();
    for (int k = ebeg + tid; k < eend; k += 256)
        atomicAdd(&cnt[stg[k].x & 255], 1);
    __syncthreads();
    int v = cnt[tid];
    scn[tid] = v;
    __syncthreads();
    for (int o = 1; o < 256; o <<= 1) {
        int a = (tid >= o) ? scn[tid - o] : 0;
        __syncthreads();
        scn[tid] += a;
        __syncthreads();
    }
    int excl = scn[tid] - v;
    int gn = (b << 8) + tid;
    if (gn < N) off[gn] = ebeg + excl;
    __syncthreads();
    cnt[tid] = excl;   // reuse as cursor
    __syncthreads();
    for (int k = ebeg + tid; k < eend; k += 256) {
        uint2 en = stg[k];
        int slot = atomicAdd(&cnt[en.x & 255], 1);
        csr_t[ebeg + slot] = (int)en.y;
    }
}

// ---------------- per-layer: xs = bf16(x); invnx[n][f] = 1/max(||x_nf||,eps) -
__global__ void prep_kernel(const float* __restrict__ x, u16* __restrict__ xs,
                            float* __restrict__ invnx, int total) {
    int i = blockIdx.x * blockDim.x + threadIdx.x;
    if (i >= total) return;
    float v = x[i];
    xs[i] = f2bf(v);
    float s = v * v;
#pragma unroll
    for (int o = 8; o >= 1; o >>= 1) s += __shfl_xor(s, o);
    if ((i & 15) == 0) invnx[i >> 4] = 1.0f / fmaxf(sqrtf(s), 1e-12f);
}

// ---------------- per-iteration: softmax prob + dcol ------------------------
// one wave per node n; lanes (k-slot = l>>2, factor = l&3); coalesced A reads.
__global__ void dcol_prob_kernel(const float* __restrict__ Acsr, const int* __restrict__ off,
                                 float* __restrict__ prob, float* __restrict__ dcol, int N) {
    int gid = blockIdx.x * blockDim.x + threadIdx.x;
    int n = gid >> 6;
    if (n >= N) return;
    int l = gid & 63;
    int s = off[n], e = off[n + 1];
    float sumf = 0.f;
    for (int base = s; base < e; base += 16) {
        int k = base + (l >> 2);
        bool valid = k < e;
        float a = valid ? Acsr[(size_t)k * 4 + (l & 3)] : 0.f;
        float mx = a;
        mx = fmaxf(mx, __shfl_xor(mx, 1));
        mx = fmaxf(mx, __shfl_xor(mx, 2));
        float ex = __expf(a - mx);
        float se = ex;
        se += __shfl_xor(se, 1);
        se += __shfl_xor(se, 2);
        float p = ex / se;
        if (valid) {
            prob[(size_t)k * 4 + (l & 3)] = p;
            sumf += p;
        }
    }
#pragma unroll
    for (int o = 4; o <= 32; o <<= 1) sumf += __shfl_xor(sumf, o);
    if (l < 4) dcol[n * 4 + l] = rsqrtf(sumf);
}

// One 64-lane wave per node, 8 edges per loop iteration.
// lane l: g = l>>3 (edge slot), m = l&7 (column octet: cols 8m..8m+7), f = m>>1.
// loop1: acc[j] = sum_k prob[k][f]*dcol[t_k][f] * xs[t_k][j]   (uint4 gathers)
// combine slots via shfl_xor(8,16,32); out[n] = dcol[n]*acc; head = out/||out_f||.
// loop2: A_csr[k][f] += sum_j head_j * ptanh5(xs[t_k][j]*invnx[t_k][f])
__global__ void message_routing_kernel(const int* __restrict__ off, const int* __restrict__ csr_t,
                                       float* __restrict__ Acsr, const float* __restrict__ prob,
                                       const u16* __restrict__ xs, const float* __restrict__ invnx,
                                       const float* __restrict__ dcol,
                                       float* __restrict__ out, int N, int doRouting) {
    int gid = blockIdx.x * blockDim.x + threadIdx.x;
    int n = gid >> 6;
    if (n >= N) return;
    int l = gid & 63;
    int g = l >> 3;
    int m = l & 7;
    int f = m >> 1;
    int s = off[n], e = off[n + 1];

    float a0 = 0.f, a1 = 0.f, a2 = 0.f, a3 = 0.f;
    float a4 = 0.f, a5 = 0.f, a6 = 0.f, a7 = 0.f;
#pragma unroll 2
    for (int k = s; k < e; k += 8) {
        int ek = k + g;
        bool valid = ek < e;
        int c = valid ? ek : s;
        int tt = csr_t[c];
        float p = valid ? prob[(size_t)c * 4 + f] * dcol[tt * 4 + f] : 0.f;
        const uint4 xv = *(const uint4*)(xs + ((size_t)tt << 6) + (m << 3));
        a0 += p * lo16(xv.x); a1 += p * hi16(xv.x);
        a2 += p * lo16(xv.y); a3 += p * hi16(xv.y);
        a4 += p * lo16(xv.z); a5 += p * hi16(xv.z);
        a6 += p * lo16(xv.w); a7 += p * hi16(xv.w);
    }
    // combine the 8 edge slots -> every lane holds full sums for its 8 cols
#pragma unroll
    for (int o = 8; o <= 32; o <<= 1) {
        a0 += __shfl_xor(a0, o); a1 += __shfl_xor(a1, o);
        a2 += __shfl_xor(a2, o); a3 += __shfl_xor(a3, o);
        a4 += __shfl_xor(a4, o); a5 += __shfl_xor(a5, o);
        a6 += __shfl_xor(a6, o); a7 += __shfl_xor(a7, o);
    }

    float dn = dcol[n * 4 + f];
    float o0 = a0 * dn, o1 = a1 * dn, o2 = a2 * dn, o3 = a3 * dn;
    float o4 = a4 * dn, o5 = a5 * dn, o6 = a6 * dn, o7 = a7 * dn;
    if (l < 8) {
        float* op = out + ((size_t)n << 6) + (m << 3);
        *(float4*)op = make_float4(o0, o1, o2, o3);
        *(float4*)(op + 4) = make_float4(o4, o5, o6, o7);
    }
    if (!doRouting) return;

    float ss = o0 * o0 + o1 * o1 + o2 * o2 + o3 * o3
             + o4 * o4 + o5 * o5 + o6 * o6 + o7 * o7;
    ss += __shfl_xor(ss, 1);
    float inv = 1.0f / fmaxf(sqrtf(ss), 1e-12f);
    float h0 = o0 * inv, h1 = o1 * inv, h2 = o2 * inv, h3 = o3 * inv;
    float h4 = o4 * inv, h5 = o5 * inv, h6 = o6 * inv, h7 = o7 * inv;

#pragma unroll 2
    for (int k = s; k < e; k += 8) {
        int ek = k + g;
        bool valid = ek < e;
        int c = valid ? ek : s;
        int tt = csr_t[c];
        float iv = invnx[tt * 4 + f];
        const uint4 xv = *(const uint4*)(xs + ((size_t)tt << 6) + (m << 3));
        float d = h0 * ptanh5(lo16(xv.x) * iv) + h1 * ptanh5(hi16(xv.x) * iv)
                + h2 * ptanh5(lo16(xv.y) * iv) + h3 * ptanh5(hi16(xv.y) * iv)
                + h4 * ptanh5(lo16(xv.z) * iv) + h5 * ptanh5(hi16(xv.z) * iv)
                + h6 * ptanh5(lo16(xv.w) * iv) + h7 * ptanh5(hi16(xv.w) * iv);
        d += __shfl_xor(d, 1);
        if (valid && (m & 1) == 0)
            Acsr[(size_t)c * 4 + f] += d;
    }
}

// acc += v; if final, acc = (acc + v) / 3
__global__ void acc_kernel(float* __restrict__ acc, const float* __restrict__ v, int n, int final_) {
    int i = blockIdx.x * blockDim.x + threadIdx.x;
    if (i >= n) return;
    float r = acc[i] + v[i];
    acc[i] = final_ ? r * (1.0f / 3.0f) : r;
}

extern "C" void kernel_launch(void* const* d_in, const int* in_sizes, int n_in,
                              void* d_out, int out_size, void* d_ws, size_t ws_size,
                              hipStream_t stream) {
    const float* user_emb = (const float*)d_in[0];
    const float* item_emb = (const float*)d_in[1];
    const int* h = (const int*)d_in[2];
    const int* t = (const int*)d_in[3];

    const int nu_elems = in_sizes[0];
    const int ni_elems = in_sizes[1];
    const int total = nu_elems + ni_elems;   // N * 64
    const int N = total / DEMB;
    const int E = in_sizes[2];
    const int NB = (N + 255) >> 8;           // buckets of 256 nodes (NB <= 1024)

    float* acc = (float*)d_out;

    // ---- workspace layout ----
    float* x     = (float*)d_ws;                    // total f32
    float* out   = x + (size_t)total;               // total f32
    float* Acsr  = out + (size_t)total;             // 4E f32
    float* prob  = Acsr + (size_t)4 * E;            // 4E f32 (aliased: CSR staging uint2[E])
    float* dcol  = prob + (size_t)4 * E;            // 4N f32
    float* invnx = dcol + (size_t)4 * N;            // 4N f32
    u16* xs      = (u16*)(invnx + (size_t)4 * N);   // total u16
    int* bcnt    = (int*)(xs + (size_t)total);      // NB
    int* bbase   = bcnt + ((NB + 3) & ~3);          // NB+1
    int* bcur    = bbase + ((NB + 4) & ~3);         // NB
    int* off     = bcur + ((NB + 3) & ~3);          // N+1
    int* csr_t   = off + ((N + 4) & ~3);            // E
    uint2* stg   = (uint2*)prob;                    // E (time-disjoint with prob)

    const int BLK = 256;
    const int gE = (E + BLK - 1) / BLK;
    const int gTot = (total + BLK - 1) / BLK;
    const int gNodeWave = (N * 64 + BLK - 1) / BLK;

    init_A_kernel<<<gE, BLK, 0, stream>>>((float4*)Acsr, E);
    concat_copy_kernel<<<gTot, BLK, 0, stream>>>(user_emb, item_emb, x, acc, nu_elems, total);

    // bucket-partitioned CSR build
    hipMemsetAsync(bcnt, 0, (size_t)NB * sizeof(int), stream);
    bcount_kernel<<<gE, BLK, 0, stream>>>(h, bcnt, E);
    bscan_kernel<<<1, 1024, 0, stream>>>(bcnt, bbase, off, NB, N, E);
    hipMemcpyAsync(bcur, bbase, (size_t)NB * sizeof(int), hipMemcpyDeviceToDevice, stream);
    bscatter_kernel<<<gE, BLK, 0, stream>>>(h, t, bcur, stg, E);
    bfinalize_kernel<<<NB, 256, 0, stream>>>(stg, bbase, off, csr_t, N);

    float* xb = x;
    float* ob = out;

    for (int layer = 0; layer < 2; ++layer) {
        prep_kernel<<<gTot, BLK, 0, stream>>>(xb, xs, invnx, total);
        for (int it = 0; it < 2; ++it) {
            bool last = (layer == 1 && it == 1);
            dcol_prob_kernel<<<gNodeWave, BLK, 0, stream>>>(Acsr, off, prob, dcol, N);
            message_routing_kernel<<<gNodeWave, BLK, 0, stream>>>(off, csr_t, Acsr, prob, xs,
                                                                  invnx, dcol, ob, N,
                                                                  last ? 0 : 1);
        }
        acc_kernel<<<gTot, BLK, 0, stream>>>(acc, ob, total, layer == 1 ? 1 : 0);
        float* tmp = xb; xb = ob; ob = tmp;
    }
}

// Round 7
// 934.221 us; speedup vs baseline: 2.1159x; 2.1159x over previous
//
#include <hip/hip_runtime.h>
#include <hip/hip_bf16.h>

#define DEMB 64
typedef unsigned short u16;

__device__ __forceinline__ float bf2f(u16 u) {
    union { unsigned int i; float f; } c; c.i = ((unsigned int)u) << 16; return c.f;
}
__device__ __forceinline__ u16 f2bf(float f) {
    union { float f; unsigned int i; } c; c.f = f;
    unsigned int r = c.i + 0x7FFF + ((c.i >> 16) & 1);
    return (u16)(r >> 16);
}

// odd 7th-order minimax tanh on [-1.02, 1.02], abs err <= ~3e-4 (inputs are
// l2-normalized so |a| <= 1 + bf16 rounding). 5 VALU ops, no transcendental.
__device__ __forceinline__ float ptanh5(float a) {
    float a2 = a * a;
    float t = fmaf(a2, -0.030095f, 0.124066f);
    t = fmaf(a2, t, -0.332377f);
    t = fmaf(a2, t, 1.0f);
    return a * t;
}

__global__ void init_A_kernel(float4* __restrict__ A, int E) {
    int e = blockIdx.x * blockDim.x + threadIdx.x;
    if (e < E) A[e] = make_float4(1.f, 1.f, 1.f, 1.f);
}

__global__ void concat_copy_kernel(const float* __restrict__ u, const float* __restrict__ it,
                                   float* __restrict__ x, float* __restrict__ acc,
                                   int nu_elems, int total) {
    int i = blockIdx.x * blockDim.x + threadIdx.x;
    if (i >= total) return;
    float v = (i < nu_elems) ? u[i] : it[i - nu_elems];
    x[i] = v;
    acc[i] = v;
}

// ---------------- CSR build (by h) — R5 scheme: per-node cursors ------------
__global__ void count_kernel(const int* __restrict__ h, int* __restrict__ counts, int E) {
    int e = blockIdx.x * blockDim.x + threadIdx.x;
    if (e < E) atomicAdd(&counts[h[e]], 1);
}

__global__ void scan1_kernel(const int* __restrict__ counts, int* __restrict__ exc,
                             int* __restrict__ bsum, int N) {
    __shared__ int s[256];
    int tid = threadIdx.x;
    int i = blockIdx.x * 256 + tid;
    int v = (i < N) ? counts[i] : 0;
    s[tid] = v;
    __syncthreads();
    for (int off = 1; off < 256; off <<= 1) {
        int a = (tid >= off) ? s[tid - off] : 0;
        __syncthreads();
        s[tid] += a;
        __syncthreads();
    }
    if (i < N) exc[i] = s[tid] - v;
    if (tid == 255) bsum[blockIdx.x] = s[255];
}

// parallel single-block exclusive scan of bsum (was a serial dependent chain)
__global__ void scan2_kernel(int* __restrict__ bsum, int nb) {
    __shared__ int s[1024];
    int tid = threadIdx.x;
    int carry = 0;
    for (int base = 0; base < nb; base += 1024) {
        int i = base + tid;
        int v = (i < nb) ? bsum[i] : 0;
        s[tid] = v;
        __syncthreads();
        for (int o = 1; o < 1024; o <<= 1) {
            int a = (tid >= o) ? s[tid - o] : 0;
            __syncthreads();
            s[tid] += a;
            __syncthreads();
        }
        if (i < nb) bsum[i] = carry + s[tid] - v;
        carry += s[1023];
        __syncthreads();
    }
}

__global__ void scan3_kernel(const int* __restrict__ exc, const int* __restrict__ bsum,
                             int* __restrict__ off, int N, int E) {
    int i = blockIdx.x * blockDim.x + threadIdx.x;
    if (i < N) off[i] = exc[i] + bsum[i >> 8];
    if (i == 0) off[N] = E;
}

__global__ void fill_kernel(const int* __restrict__ h, const int* __restrict__ t,
                            int* __restrict__ cur, int* __restrict__ csr_t, int E) {
    int e = blockIdx.x * blockDim.x + threadIdx.x;
    if (e >= E) return;
    int p = atomicAdd(&cur[h[e]], 1);
    csr_t[p] = t[e];
}

// ---------------- per-layer: invnx[n][f] = 1/max(||x_nf||,eps) ----------------
__global__ void norm_kernel(const float* __restrict__ x, float* __restrict__ invnx, int total) {
    int i = blockIdx.x * blockDim.x + threadIdx.x;
    if (i >= total) return;
    float v = x[i];
    float s = v * v;
#pragma unroll
    for (int o = 8; o >= 1; o >>= 1) s += __shfl_xor(s, o);
    if ((i & 15) == 0) invnx[i >> 4] = 1.0f / fmaxf(sqrtf(s), 1e-12f);
}

// ---------------- per-iteration: fused softmax/prob + dcol + tailscale + xs ----
// one wave per node n. lanes (k-slot = l>>2, factor = l&3) for the A pass;
// epilogue: every lane l writes xs[n*64+l] = bf16(x * dcol[n][l>>4]).
__global__ void dcol_prob_xs_kernel(const float* __restrict__ Acsr, const int* __restrict__ off,
                                    const float* __restrict__ x, const float* __restrict__ invnx,
                                    float* __restrict__ prob, float* __restrict__ dcol,
                                    float* __restrict__ tailscale, u16* __restrict__ xs, int N) {
    int gid = blockIdx.x * blockDim.x + threadIdx.x;
    int n = gid >> 6;
    if (n >= N) return;
    int l = gid & 63;
    int s = off[n], e = off[n + 1];
    float sumf = 0.f;
    for (int base = s; base < e; base += 16) {
        int k = base + (l >> 2);
        bool valid = k < e;
        float a = valid ? Acsr[(size_t)k * 4 + (l & 3)] : 0.f;
        float mx = a;
        mx = fmaxf(mx, __shfl_xor(mx, 1));
        mx = fmaxf(mx, __shfl_xor(mx, 2));
        float ex = __expf(a - mx);
        float se = ex;
        se += __shfl_xor(se, 1);
        se += __shfl_xor(se, 2);
        float p = ex / se;
        if (valid) {
            prob[(size_t)k * 4 + (l & 3)] = p;
            sumf += p;
        }
    }
#pragma unroll
    for (int o = 4; o <= 32; o <<= 1) sumf += __shfl_xor(sumf, o);
    // lane l holds rowsum for factor (l&3)
    float dn = rsqrtf(sumf);
    if (l < 4) {
        dcol[n * 4 + l] = dn;
        tailscale[n * 4 + l] = invnx[n * 4 + l] * sqrtf(sumf);  // invnx / dcol
    }
    float myd = __shfl(dn, l >> 4);  // dcol for the factor owning column l
    size_t idx = ((size_t)n << 6) + l;
    xs[idx] = f2bf(x[idx] * myd);
}

// One 64-lane wave per node, 8 edges per loop trip (two 4-edge slots).
// lane l: g = l>>4 (edge slot), m = l&15 (column quad: cols 4m..4m+3), f = m>>2.
// loop1: acc[j] = sum_k prob[k][f] * xs[t_k][j]  (xs pre-scaled by dcol[t])
// The first 2 trips (16 edges, ~80% of nodes fully) cache {t, xs row} in
// registers; loop2 consumes the cache instead of re-gathering.
// combine slots via shfl_xor(16,32); out[n] = dcol[n]*acc; head = out/||out_f||.
// loop2: A_csr[k][f] += sum_j head_j * ptanh5(xs[t_k][j]*tailscale[t_k][f])
__global__ void message_routing_kernel(const int* __restrict__ off, const int* __restrict__ csr_t,
                                       float* __restrict__ Acsr, const float* __restrict__ prob,
                                       const u16* __restrict__ xs, const float* __restrict__ tailscale,
                                       const float* __restrict__ dcol,
                                       float* __restrict__ out, int N, int doRouting) {
    int gid = blockIdx.x * blockDim.x + threadIdx.x;
    int n = gid >> 6;
    if (n >= N) return;
    int l = gid & 63;
    int g = l >> 4;
    int m = l & 15;
    int f = m >> 2;
    int s = off[n], e = off[n + 1];

    float a0 = 0.f, a1 = 0.f, a2 = 0.f, a3 = 0.f;

    auto gather = [&](int k, int& t1, int& t2, float& p1, float& p2,
                      ushort4& xv1, ushort4& xv2) {
        int e1 = k + g, e2 = e1 + 4;
        bool v1 = e1 < e, v2 = e2 < e;
        int c1 = v1 ? e1 : s;
        int c2 = v2 ? e2 : s;
        t1 = csr_t[c1]; t2 = csr_t[c2];
        p1 = v1 ? prob[(size_t)c1 * 4 + f] : 0.f;
        p2 = v2 ? prob[(size_t)c2 * 4 + f] : 0.f;
        xv1 = *(const ushort4*)(xs + ((size_t)t1 << 6) + (m << 2));
        xv2 = *(const ushort4*)(xs + ((size_t)t2 << 6) + (m << 2));
    };
    auto accum = [&](float p1, float p2, const ushort4& xv1, const ushort4& xv2) {
        a0 += p1 * bf2f(xv1.x) + p2 * bf2f(xv2.x);
        a1 += p1 * bf2f(xv1.y) + p2 * bf2f(xv2.y);
        a2 += p1 * bf2f(xv1.z) + p2 * bf2f(xv2.z);
        a3 += p1 * bf2f(xv1.w) + p2 * bf2f(xv2.w);
    };

    // peeled trips A (k=s) and B (k=s+8): cached in registers (static indexing)
    bool hasA = s < e, hasB = s + 8 < e;
    int tA1, tA2, tB1, tB2;
    float pA1, pA2, pB1, pB2;
    ushort4 xA1, xA2, xB1, xB2;
    if (hasA) { gather(s, tA1, tA2, pA1, pA2, xA1, xA2); accum(pA1, pA2, xA1, xA2); }
    if (hasB) { gather(s + 8, tB1, tB2, pB1, pB2, xB1, xB2); accum(pB1, pB2, xB1, xB2); }
#pragma unroll 2
    for (int k = s + 16; k < e; k += 8) {
        int t1, t2; float p1, p2; ushort4 xv1, xv2;
        gather(k, t1, t2, p1, p2, xv1, xv2);
        accum(p1, p2, xv1, xv2);
    }

    // combine the 4 edge slots -> every lane holds the full sums for its cols
    a0 += __shfl_xor(a0, 16); a1 += __shfl_xor(a1, 16);
    a2 += __shfl_xor(a2, 16); a3 += __shfl_xor(a3, 16);
    a0 += __shfl_xor(a0, 32); a1 += __shfl_xor(a1, 32);
    a2 += __shfl_xor(a2, 32); a3 += __shfl_xor(a3, 32);

    float dn = dcol[n * 4 + f];
    float o0 = a0 * dn, o1 = a1 * dn, o2 = a2 * dn, o3 = a3 * dn;
    if (l < 16) {
        *(float4*)(out + ((size_t)n << 6) + (m << 2)) = make_float4(o0, o1, o2, o3);
    }
    if (!doRouting) return;

    float ss = o0 * o0 + o1 * o1 + o2 * o2 + o3 * o3;
    ss += __shfl_xor(ss, 1);
    ss += __shfl_xor(ss, 2);
    float inv = 1.0f / fmaxf(sqrtf(ss), 1e-12f);
    float h0 = o0 * inv, h1 = o1 * inv, h2 = o2 * inv, h3 = o3 * inv;

    auto route = [&](int k, int t1, int t2, const ushort4& xv1, const ushort4& xv2) {
        int e1 = k + g, e2 = e1 + 4;
        bool v1 = e1 < e, v2 = e2 < e;
        float ts1 = tailscale[t1 * 4 + f];
        float ts2 = tailscale[t2 * 4 + f];
        float d1 = h0 * ptanh5(bf2f(xv1.x) * ts1) + h1 * ptanh5(bf2f(xv1.y) * ts1)
                 + h2 * ptanh5(bf2f(xv1.z) * ts1) + h3 * ptanh5(bf2f(xv1.w) * ts1);
        float d2 = h0 * ptanh5(bf2f(xv2.x) * ts2) + h1 * ptanh5(bf2f(xv2.y) * ts2)
                 + h2 * ptanh5(bf2f(xv2.z) * ts2) + h3 * ptanh5(bf2f(xv2.w) * ts2);
        d1 += __shfl_xor(d1, 1); d1 += __shfl_xor(d1, 2);
        d2 += __shfl_xor(d2, 1); d2 += __shfl_xor(d2, 2);
        if ((m & 3) == 0) {
            if (v1) Acsr[(size_t)e1 * 4 + f] += d1;
            if (v2) Acsr[(size_t)e2 * 4 + f] += d2;
        }
    };

    if (hasA) route(s, tA1, tA2, xA1, xA2);       // cached: no re-gather
    if (hasB) route(s + 8, tB1, tB2, xB1, xB2);   // cached: no re-gather
#pragma unroll 2
    for (int k = s + 16; k < e; k += 8) {
        int e1 = k + g, e2 = e1 + 4;
        bool v1 = e1 < e, v2 = e2 < e;
        int c1 = v1 ? e1 : s;
        int c2 = v2 ? e2 : s;
        int t1 = csr_t[c1], t2 = csr_t[c2];
        ushort4 xv1 = *(const ushort4*)(xs + ((size_t)t1 << 6) + (m << 2));
        ushort4 xv2 = *(const ushort4*)(xs + ((size_t)t2 << 6) + (m << 2));
        route(k, t1, t2, xv1, xv2);
    }
}

// acc += v; if final, acc = (acc + v) / 3
__global__ void acc_kernel(float* __restrict__ acc, const float* __restrict__ v, int n, int final_) {
    int i = blockIdx.x * blockDim.x + threadIdx.x;
    if (i >= n) return;
    float r = acc[i] + v[i];
    acc[i] = final_ ? r * (1.0f / 3.0f) : r;
}

extern "C" void kernel_launch(void* const* d_in, const int* in_sizes, int n_in,
                              void* d_out, int out_size, void* d_ws, size_t ws_size,
                              hipStream_t stream) {
    const float* user_emb = (const float*)d_in[0];
    const float* item_emb = (const float*)d_in[1];
    const int* h = (const int*)d_in[2];
    const int* t = (const int*)d_in[3];

    const int nu_elems = in_sizes[0];
    const int ni_elems = in_sizes[1];
    const int total = nu_elems + ni_elems;   // N * 64
    const int N = total / DEMB;
    const int E = in_sizes[2];
    const int nb = (N + 255) / 256;

    float* acc = (float*)d_out;

    // ---- workspace layout ----
    float* x        = (float*)d_ws;                    // total f32
    float* out      = x + (size_t)total;               // total f32
    float* Acsr     = out + (size_t)total;             // 4E f32
    float* prob     = Acsr + (size_t)4 * E;            // 4E f32
    float* dcol     = prob + (size_t)4 * E;            // 4N f32
    float* tailsc   = dcol + (size_t)4 * N;            // 4N f32
    float* invnx    = tailsc + (size_t)4 * N;          // 4N f32
    u16* xs         = (u16*)(invnx + (size_t)4 * N);   // total u16
    int* counts     = (int*)(xs + (size_t)total);      // N
    int* off        = counts + N;                      // N+4
    int* cur        = off + N + 4;                     // N
    int* exc        = cur + N;                         // N
    int* bsum       = exc + N;                         // nb (padded)
    int* csr_t      = bsum + ((nb + 3) & ~3);          // E

    const int BLK = 256;
    const int gE = (E + BLK - 1) / BLK;
    const int gTot = (total + BLK - 1) / BLK;
    const int gNodeWave = (N * 64 + BLK - 1) / BLK;

    init_A_kernel<<<gE, BLK, 0, stream>>>((float4*)Acsr, E);
    concat_copy_kernel<<<gTot, BLK, 0, stream>>>(user_emb, item_emb, x, acc, nu_elems, total);

    // CSR build (R5 scheme: 100K per-node cursors -> low atomic contention)
    hipMemsetAsync(counts, 0, (size_t)N * sizeof(int), stream);
    count_kernel<<<gE, BLK, 0, stream>>>(h, counts, E);
    scan1_kernel<<<nb, 256, 0, stream>>>(counts, exc, bsum, N);
    scan2_kernel<<<1, 1024, 0, stream>>>(bsum, nb);
    scan3_kernel<<<(N + BLK - 1) / BLK, BLK, 0, stream>>>(exc, bsum, off, N, E);
    hipMemcpyAsync(cur, off, (size_t)N * sizeof(int), hipMemcpyDeviceToDevice, stream);
    fill_kernel<<<gE, BLK, 0, stream>>>(h, t, cur, csr_t, E);

    float* xb = x;
    float* ob = out;

    for (int layer = 0; layer < 2; ++layer) {
        norm_kernel<<<gTot, BLK, 0, stream>>>(xb, invnx, total);
        for (int it = 0; it < 2; ++it) {
            bool last = (layer == 1 && it == 1);
            dcol_prob_xs_kernel<<<gNodeWave, BLK, 0, stream>>>(Acsr, off, xb, invnx, prob,
                                                               dcol, tailsc, xs, N);
            message_routing_kernel<<<gNodeWave, BLK, 0, stream>>>(off, csr_t, Acsr, prob, xs,
                                                                  tailsc, dcol, ob, N,
                                                                  last ? 0 : 1);
        }
        acc_kernel<<<gTot, BLK, 0, stream>>>(acc, ob, total, layer == 1 ? 1 : 0);
        float* tmp = xb; xb = ob; ob = tmp;
    }
}

// Round 8
// 746.739 us; speedup vs baseline: 2.6471x; 1.2511x over previous
//
#include <hip/hip_runtime.h>
#include <hip/hip_bf16.h>

#define DEMB 64
typedef unsigned short u16;

__device__ __forceinline__ float bf2f(u16 u) {
    union { unsigned int i; float f; } c; c.i = ((unsigned int)u) << 16; return c.f;
}
__device__ __forceinline__ u16 f2bf(float f) {
    union { float f; unsigned int i; } c; c.f = f;
    unsigned int r = c.i + 0x7FFF + ((c.i >> 16) & 1);
    return (u16)(r >> 16);
}

// odd 7th-order minimax tanh on [-1.02, 1.02], abs err <= ~3e-4
__device__ __forceinline__ float ptanh5(float a) {
    float a2 = a * a;
    float t = fmaf(a2, -0.030095f, 0.124066f);
    t = fmaf(a2, t, -0.332377f);
    t = fmaf(a2, t, 1.0f);
    return a * t;
}

__global__ void init_A_kernel(float4* __restrict__ A, int E) {
    int e = blockIdx.x * blockDim.x + threadIdx.x;
    if (e < E) A[e] = make_float4(1.f, 1.f, 1.f, 1.f);
}

__global__ void concat_copy_kernel(const float* __restrict__ u, const float* __restrict__ it,
                                   float* __restrict__ x, float* __restrict__ acc,
                                   int nu_elems, int total) {
    int i = blockIdx.x * blockDim.x + threadIdx.x;
    if (i >= total) return;
    float v = (i < nu_elems) ? u[i] : it[i - nu_elems];
    x[i] = v;
    acc[i] = v;
}

// ============ CSR build v3: deterministic histogram radix (no contended atomics)
// bucket = h >> 8 (NB <= 1024). NBLK scatter blocks, per-block LDS histograms.

__global__ void hist_kernel(const int* __restrict__ h, int* __restrict__ ghist,
                            int E, int EPB, int NB) {
    __shared__ int bins[1024];
    int b = blockIdx.x, tid = threadIdx.x;
    for (int j = tid; j < NB; j += 256) bins[j] = 0;
    __syncthreads();
    int s = b * EPB, e = min(s + EPB, E);
    for (int k = s + tid; k < e; k += 256)
        atomicAdd(&bins[((unsigned)h[k]) >> 8], 1);
    __syncthreads();
    for (int j = tid; j < NB; j += 256) ghist[j * gridDim.x + b] = bins[j];
}

// one block per bucket: btot[j] = sum over blocks
__global__ void btot_kernel(const int* __restrict__ ghist, int* __restrict__ btot) {
    __shared__ int s[256];
    int j = blockIdx.x, tid = threadIdx.x;
    s[tid] = ghist[j * 256 + tid];
    __syncthreads();
    for (int o = 128; o >= 1; o >>= 1) {
        if (tid < o) s[tid] += s[tid + o];
        __syncthreads();
    }
    if (tid == 0) btot[j] = s[0];
}

// single block: exclusive scan of bucket totals -> bbase[NB+1]
__global__ void bscan_kernel(const int* __restrict__ btot, int* __restrict__ bbase,
                             int NB, int E) {
    __shared__ int s[1024];
    int tid = threadIdx.x;
    int v = (tid < NB) ? btot[tid] : 0;
    s[tid] = v;
    __syncthreads();
    for (int o = 1; o < 1024; o <<= 1) {
        int a = (tid >= o) ? s[tid - o] : 0;
        __syncthreads();
        s[tid] += a;
        __syncthreads();
    }
    if (tid < NB) bbase[tid] = s[tid] - v;
    if (tid == 0) bbase[NB] = E;
}

// one block per bucket: exclusive scan over its per-block counts + bbase
__global__ void bofs_kernel(int* __restrict__ ghist, const int* __restrict__ bbase) {
    __shared__ int s[256];
    int j = blockIdx.x, tid = threadIdx.x;
    int v = ghist[j * 256 + tid];
    s[tid] = v;
    __syncthreads();
    for (int o = 1; o < 256; o <<= 1) {
        int a = (tid >= o) ? s[tid - o] : 0;
        __syncthreads();
        s[tid] += a;
        __syncthreads();
    }
    ghist[j * 256 + tid] = bbase[j] + s[tid] - v;
}

// scatter packed (h&255)<<18 | t into bucket-clustered staging, LDS cursors only
__global__ void scatter_kernel(const int* __restrict__ h, const int* __restrict__ t,
                               const int* __restrict__ ghist, unsigned* __restrict__ stg,
                               int E, int EPB, int NB) {
    __shared__ int cur[1024];
    int b = blockIdx.x, tid = threadIdx.x;
    for (int j = tid; j < NB; j += 256) cur[j] = ghist[j * gridDim.x + b];
    __syncthreads();
    int s = b * EPB, e = min(s + EPB, E);
    for (int k = s + tid; k < e; k += 256) {
        unsigned hh = (unsigned)h[k];
        int pos = atomicAdd(&cur[hh >> 8], 1);
        stg[pos] = ((hh & 255u) << 18) | (unsigned)t[k];
    }
}

// one block per bucket: per-node LDS count+scan, contiguous csr_t writes
__global__ void finalize_kernel(const unsigned* __restrict__ stg, const int* __restrict__ bbase,
                                int* __restrict__ off, int* __restrict__ csr_t, int N, int E) {
    __shared__ int cnt[256];
    __shared__ int scn[256];
    int b = blockIdx.x, tid = threadIdx.x;
    int ebeg = bbase[b], eend = bbase[b + 1];
    cnt[tid] = 0;
    __syncthreads();
    for (int k = ebeg + tid; k < eend; k += 256)
        atomicAdd(&cnt[(stg[k] >> 18) & 255u], 1);
    __syncthreads();
    int v = cnt[tid];
    scn[tid] = v;
    __syncthreads();
    for (int o = 1; o < 256; o <<= 1) {
        int a = (tid >= o) ? scn[tid - o] : 0;
        __syncthreads();
        scn[tid] += a;
        __syncthreads();
    }
    int excl = scn[tid] - v;
    int gn = (b << 8) + tid;
    if (gn < N) off[gn] = ebeg + excl;
    if (b == 0 && tid == 0) off[N] = E;
    __syncthreads();
    cnt[tid] = excl;   // reuse as cursor
    __syncthreads();
    for (int k = ebeg + tid; k < eend; k += 256) {
        unsigned en = stg[k];
        int slot = atomicAdd(&cnt[(en >> 18) & 255u], 1);
        csr_t[ebeg + slot] = (int)(en & 0x3FFFFu);
    }
}

// bootstrap: A=1 uniform -> prob=0.25, rowsum=deg/4, dcol=2/sqrt(deg)
__global__ void dcol0_kernel(const int* __restrict__ off, float* __restrict__ dcol, int N) {
    int n = blockIdx.x * blockDim.x + threadIdx.x;
    if (n >= N) return;
    float v = 2.0f * rsqrtf((float)(off[n + 1] - off[n]));
    *(float4*)(dcol + (size_t)n * 4) = make_float4(v, v, v, v);
}

// ============ per-layer: xs = bf16(x); invnx[n][f] = 1/max(||x_nf||,eps)
__global__ void prep_kernel(const float* __restrict__ x, u16* __restrict__ xs,
                            float* __restrict__ invnx, int total) {
    int i = blockIdx.x * blockDim.x + threadIdx.x;
    if (i >= total) return;
    float v = x[i];
    xs[i] = f2bf(v);
    float s = v * v;
#pragma unroll
    for (int o = 8; o >= 1; o >>= 1) s += __shfl_xor(s, o);
    if ((i & 15) == 0) invnx[i >> 4] = 1.0f / fmaxf(sqrtf(s), 1e-12f);
}

// ============ fused message + routing + next-iteration softmax/dcol
// One 64-lane wave per node. lane l: g=l>>4 (edge slot), m=l&15 (col quad), f=m>>2.
// loop1: acc[j] = sum_k prob[k][f]*dcol_in[t_k][f]*xs[t_k][j]
// head = acc/||acc_f|| (dcol[n] scale-invariant).  WOUT: out[n]=dcol_in[n]*acc.
// loop2 (ROUTE): newA = A + dot16(head, ptanh5(xs[t]*invnx[t])); softmax over f
// (shfl xor 4,8) -> prob_next; rowsum -> dcol_out[n] = rsqrt(sum).
template <bool UNI, bool WOUT, bool ROUTE>
__global__ void message_kernel(const int* __restrict__ off, const int* __restrict__ csr_t,
                               float* __restrict__ Acsr, float* __restrict__ prob,
                               const u16* __restrict__ xs, const float* __restrict__ invnx,
                               const float* __restrict__ dcol_in, float* __restrict__ dcol_out,
                               float* __restrict__ out, int N) {
    int gid = blockIdx.x * blockDim.x + threadIdx.x;
    int n = gid >> 6;
    if (n >= N) return;
    int l = gid & 63;
    int g = l >> 4;
    int m = l & 15;
    int f = m >> 2;
    int s = off[n], e = off[n + 1];

    float a0 = 0.f, a1 = 0.f, a2 = 0.f, a3 = 0.f;

    auto gather = [&](int k, int& t1, int& t2, ushort4& xv1, ushort4& xv2) {
        int e1 = k + g, e2 = e1 + 4;
        bool v1 = e1 < e, v2 = e2 < e;
        int c1 = v1 ? e1 : s;
        int c2 = v2 ? e2 : s;
        t1 = csr_t[c1]; t2 = csr_t[c2];
        float p1, p2;
        if (UNI) { p1 = 0.25f; p2 = 0.25f; }
        else { p1 = prob[(size_t)c1 * 4 + f]; p2 = prob[(size_t)c2 * 4 + f]; }
        p1 = v1 ? p1 * dcol_in[t1 * 4 + f] : 0.f;
        p2 = v2 ? p2 * dcol_in[t2 * 4 + f] : 0.f;
        xv1 = *(const ushort4*)(xs + ((size_t)t1 << 6) + (m << 2));
        xv2 = *(const ushort4*)(xs + ((size_t)t2 << 6) + (m << 2));
        a0 += p1 * bf2f(xv1.x) + p2 * bf2f(xv2.x);
        a1 += p1 * bf2f(xv1.y) + p2 * bf2f(xv2.y);
        a2 += p1 * bf2f(xv1.z) + p2 * bf2f(xv2.z);
        a3 += p1 * bf2f(xv1.w) + p2 * bf2f(xv2.w);
    };

    // first 16 edges cached in registers for loop2 (static indexing)
    bool hasA = s < e, hasB = s + 8 < e;
    int tA1, tA2, tB1, tB2;
    ushort4 xA1, xA2, xB1, xB2;
    if (hasA) gather(s, tA1, tA2, xA1, xA2);
    if (hasB) gather(s + 8, tB1, tB2, xB1, xB2);
#pragma unroll 2
    for (int k = s + 16; k < e; k += 8) {
        int t1, t2; ushort4 xv1, xv2;
        gather(k, t1, t2, xv1, xv2);
    }

    // combine the 4 edge slots
    a0 += __shfl_xor(a0, 16); a1 += __shfl_xor(a1, 16);
    a2 += __shfl_xor(a2, 16); a3 += __shfl_xor(a3, 16);
    a0 += __shfl_xor(a0, 32); a1 += __shfl_xor(a1, 32);
    a2 += __shfl_xor(a2, 32); a3 += __shfl_xor(a3, 32);

    if (WOUT) {
        float dn = dcol_in[n * 4 + f];
        if (l < 16) {
            *(float4*)(out + ((size_t)n << 6) + (m << 2)) =
                make_float4(a0 * dn, a1 * dn, a2 * dn, a3 * dn);
        }
    }
    if (!ROUTE) return;

    // head = l2norm per factor (scale-invariant: dcol[n] factor drops out)
    float ss = a0 * a0 + a1 * a1 + a2 * a2 + a3 * a3;
    ss += __shfl_xor(ss, 1);
    ss += __shfl_xor(ss, 2);
    float inv = 1.0f / fmaxf(sqrtf(ss), 1e-12f);
    float h0 = a0 * inv, h1 = a1 * inv, h2 = a2 * inv, h3 = a3 * inv;

    float rowsumf = 0.f;

    auto route = [&](int k, int t1, int t2, const ushort4& xv1, const ushort4& xv2) {
        int e1 = k + g, e2 = e1 + 4;
        bool v1 = e1 < e, v2 = e2 < e;
        int c1 = v1 ? e1 : s;
        int c2 = v2 ? e2 : s;
        float iv1 = invnx[t1 * 4 + f];
        float iv2 = invnx[t2 * 4 + f];
        float d1 = h0 * ptanh5(bf2f(xv1.x) * iv1) + h1 * ptanh5(bf2f(xv1.y) * iv1)
                 + h2 * ptanh5(bf2f(xv1.z) * iv1) + h3 * ptanh5(bf2f(xv1.w) * iv1);
        float d2 = h0 * ptanh5(bf2f(xv2.x) * iv2) + h1 * ptanh5(bf2f(xv2.y) * iv2)
                 + h2 * ptanh5(bf2f(xv2.z) * iv2) + h3 * ptanh5(bf2f(xv2.w) * iv2);
        d1 += __shfl_xor(d1, 1); d1 += __shfl_xor(d1, 2);
        d2 += __shfl_xor(d2, 1); d2 += __shfl_xor(d2, 2);
        float na1 = Acsr[(size_t)c1 * 4 + f] + d1;
        float na2 = Acsr[(size_t)c2 * 4 + f] + d2;
        // softmax over the 4 factors (lane bits 2..3 of m)
        float mx1 = fmaxf(na1, __shfl_xor(na1, 4)); mx1 = fmaxf(mx1, __shfl_xor(mx1, 8));
        float mx2 = fmaxf(na2, __shfl_xor(na2, 4)); mx2 = fmaxf(mx2, __shfl_xor(mx2, 8));
        float ex1 = __expf(na1 - mx1);
        float ex2 = __expf(na2 - mx2);
        float se1 = ex1 + __shfl_xor(ex1, 4); se1 += __shfl_xor(se1, 8);
        float se2 = ex2 + __shfl_xor(ex2, 4); se2 += __shfl_xor(se2, 8);
        float p1 = ex1 / se1;
        float p2 = ex2 / se2;
        if ((m & 3) == 0) {
            if (v1) { Acsr[(size_t)e1 * 4 + f] = na1; prob[(size_t)e1 * 4 + f] = p1; }
            if (v2) { Acsr[(size_t)e2 * 4 + f] = na2; prob[(size_t)e2 * 4 + f] = p2; }
        }
        rowsumf += (v1 ? p1 : 0.f) + (v2 ? p2 : 0.f);
    };

    if (hasA) route(s, tA1, tA2, xA1, xA2);        // cached rows, no re-gather
    if (hasB) route(s + 8, tB1, tB2, xB1, xB2);
#pragma unroll 2
    for (int k = s + 16; k < e; k += 8) {
        int e1 = k + g, e2 = e1 + 4;
        bool v1 = e1 < e, v2 = e2 < e;
        int c1 = v1 ? e1 : s;
        int c2 = v2 ? e2 : s;
        int t1 = csr_t[c1], t2 = csr_t[c2];
        ushort4 xv1 = *(const ushort4*)(xs + ((size_t)t1 << 6) + (m << 2));
        ushort4 xv2 = *(const ushort4*)(xs + ((size_t)t2 << 6) + (m << 2));
        route(k, t1, t2, xv1, xv2);
    }

    rowsumf += __shfl_xor(rowsumf, 16);
    rowsumf += __shfl_xor(rowsumf, 32);
    if (l < 16 && (m & 3) == 0) dcol_out[n * 4 + f] = rsqrtf(rowsumf);
}

// acc += v; if final, acc = (acc + v) / 3
__global__ void acc_kernel(float* __restrict__ acc, const float* __restrict__ v, int n, int final_) {
    int i = blockIdx.x * blockDim.x + threadIdx.x;
    if (i >= n) return;
    float r = acc[i] + v[i];
    acc[i] = final_ ? r * (1.0f / 3.0f) : r;
}

extern "C" void kernel_launch(void* const* d_in, const int* in_sizes, int n_in,
                              void* d_out, int out_size, void* d_ws, size_t ws_size,
                              hipStream_t stream) {
    const float* user_emb = (const float*)d_in[0];
    const float* item_emb = (const float*)d_in[1];
    const int* h = (const int*)d_in[2];
    const int* t = (const int*)d_in[3];

    const int nu_elems = in_sizes[0];
    const int ni_elems = in_sizes[1];
    const int total = nu_elems + ni_elems;   // N * 64
    const int N = total / DEMB;
    const int E = in_sizes[2];
    const int NB = (N + 255) >> 8;           // buckets (<= 1024)
    const int NBLK = 256;
    const int EPB = (E + NBLK - 1) / NBLK;

    float* acc = (float*)d_out;

    // ---- workspace layout ----
    float* x     = (float*)d_ws;                    // total f32
    float* out   = x + (size_t)total;               // total f32
    float* Acsr  = out + (size_t)total;             // 4E f32
    float* prob  = Acsr + (size_t)4 * E;            // 4E f32 (first E aliased as stg)
    float* dcolA = prob + (size_t)4 * E;            // 4N f32
    float* dcolB = dcolA + (size_t)4 * N;           // 4N f32
    float* invnx = dcolB + (size_t)4 * N;           // 4N f32
    u16* xs      = (u16*)(invnx + (size_t)4 * N);   // total u16
    int* ghist   = (int*)(xs + (size_t)total);      // NB*256
    int* btot    = ghist + (size_t)NB * 256;        // NB
    int* bbase   = btot + ((NB + 3) & ~3);          // NB+1
    int* off     = bbase + ((NB + 5) & ~3);         // N+1
    int* csr_t   = off + ((N + 4) & ~3);            // E
    unsigned* stg = (unsigned*)prob;                // E (time-disjoint with prob)

    const int BLK = 256;
    const int gE = (E + BLK - 1) / BLK;
    const int gTot = (total + BLK - 1) / BLK;
    const int gN = (N + BLK - 1) / BLK;
    const int gNodeWave = (N * 64 + BLK - 1) / BLK;

    concat_copy_kernel<<<gTot, BLK, 0, stream>>>(user_emb, item_emb, x, acc, nu_elems, total);

    // CSR build v3 (deterministic, no contended global atomics)
    hist_kernel<<<NBLK, 256, 0, stream>>>(h, ghist, E, EPB, NB);
    btot_kernel<<<NB, 256, 0, stream>>>(ghist, btot);
    bscan_kernel<<<1, 1024, 0, stream>>>(btot, bbase, NB, E);
    bofs_kernel<<<NB, 256, 0, stream>>>(ghist, bbase);
    scatter_kernel<<<NBLK, 256, 0, stream>>>(h, t, ghist, stg, E, EPB, NB);
    finalize_kernel<<<NB, 256, 0, stream>>>(stg, bbase, off, csr_t, N, E);

    init_A_kernel<<<gE, BLK, 0, stream>>>((float4*)Acsr, E);
    dcol0_kernel<<<gN, BLK, 0, stream>>>(off, dcolA, N);

    // ---- layer 0 (x fixed; out written only on layer-final iteration) ----
    prep_kernel<<<gTot, BLK, 0, stream>>>(x, xs, invnx, total);
    message_kernel<true, false, true><<<gNodeWave, BLK, 0, stream>>>(
        off, csr_t, Acsr, prob, xs, invnx, dcolA, dcolB, out, N);
    message_kernel<false, true, true><<<gNodeWave, BLK, 0, stream>>>(
        off, csr_t, Acsr, prob, xs, invnx, dcolB, dcolA, out, N);
    acc_kernel<<<gTot, BLK, 0, stream>>>(acc, out, total, 0);

    // ---- layer 1 (input = out; result into x buffer) ----
    prep_kernel<<<gTot, BLK, 0, stream>>>(out, xs, invnx, total);
    message_kernel<false, false, true><<<gNodeWave, BLK, 0, stream>>>(
        off, csr_t, Acsr, prob, xs, invnx, dcolA, dcolB, x, N);
    message_kernel<false, true, false><<<gNodeWave, BLK, 0, stream>>>(
        off, csr_t, Acsr, prob, xs, invnx, dcolB, dcolA, x, N);
    acc_kernel<<<gTot, BLK, 0, stream>>>(acc, x, total, 1);
}

// Round 9
// 608.108 us; speedup vs baseline: 3.2506x; 1.2280x over previous
//
#include <hip/hip_runtime.h>
#include <hip/hip_bf16.h>

#define DEMB 64
typedef unsigned short u16;

__device__ __forceinline__ u16 f2bf(float f) {
    union { float f; unsigned int i; } c; c.f = f;
    unsigned int r = c.i + 0x7FFF + ((c.i >> 16) & 1);
    return (u16)(r >> 16);
}
__device__ __forceinline__ float lo16(unsigned int w) {
    union { unsigned int i; float f; } c; c.i = w << 16; return c.f;
}
__device__ __forceinline__ float hi16(unsigned int w) {
    union { unsigned int i; float f; } c; c.i = w & 0xFFFF0000u; return c.f;
}

// odd 7th-order minimax tanh on [-1.02, 1.02], abs err <= ~3e-4
__device__ __forceinline__ float ptanh5(float a) {
    float a2 = a * a;
    float t = fmaf(a2, -0.030095f, 0.124066f);
    t = fmaf(a2, t, -0.332377f);
    t = fmaf(a2, t, 1.0f);
    return a * t;
}

__global__ void init_A_kernel(float4* __restrict__ A, int E) {
    int e = blockIdx.x * blockDim.x + threadIdx.x;
    if (e < E) A[e] = make_float4(1.f, 1.f, 1.f, 1.f);
}

__global__ void concat_copy_kernel(const float* __restrict__ u, const float* __restrict__ it,
                                   float* __restrict__ x, float* __restrict__ acc,
                                   int nu_elems, int total) {
    int i = blockIdx.x * blockDim.x + threadIdx.x;
    if (i >= total) return;
    float v = (i < nu_elems) ? u[i] : it[i - nu_elems];
    x[i] = v;
    acc[i] = v;
}

// ============ CSR build v3: deterministic histogram radix (no contended atomics)
__global__ void hist_kernel(const int* __restrict__ h, int* __restrict__ ghist,
                            int E, int EPB, int NB) {
    __shared__ int bins[1024];
    int b = blockIdx.x, tid = threadIdx.x;
    for (int j = tid; j < NB; j += 256) bins[j] = 0;
    __syncthreads();
    int s = b * EPB, e = min(s + EPB, E);
    for (int k = s + tid; k < e; k += 256)
        atomicAdd(&bins[((unsigned)h[k]) >> 8], 1);
    __syncthreads();
    for (int j = tid; j < NB; j += 256) ghist[j * gridDim.x + b] = bins[j];
}

__global__ void btot_kernel(const int* __restrict__ ghist, int* __restrict__ btot) {
    __shared__ int s[256];
    int j = blockIdx.x, tid = threadIdx.x;
    s[tid] = ghist[j * 256 + tid];
    __syncthreads();
    for (int o = 128; o >= 1; o >>= 1) {
        if (tid < o) s[tid] += s[tid + o];
        __syncthreads();
    }
    if (tid == 0) btot[j] = s[0];
}

__global__ void bscan_kernel(const int* __restrict__ btot, int* __restrict__ bbase,
                             int NB, int E) {
    __shared__ int s[1024];
    int tid = threadIdx.x;
    int v = (tid < NB) ? btot[tid] : 0;
    s[tid] = v;
    __syncthreads();
    for (int o = 1; o < 1024; o <<= 1) {
        int a = (tid >= o) ? s[tid - o] : 0;
        __syncthreads();
        s[tid] += a;
        __syncthreads();
    }
    if (tid < NB) bbase[tid] = s[tid] - v;
    if (tid == 0) bbase[NB] = E;
}

__global__ void bofs_kernel(int* __restrict__ ghist, const int* __restrict__ bbase) {
    __shared__ int s[256];
    int j = blockIdx.x, tid = threadIdx.x;
    int v = ghist[j * 256 + tid];
    s[tid] = v;
    __syncthreads();
    for (int o = 1; o < 256; o <<= 1) {
        int a = (tid >= o) ? s[tid - o] : 0;
        __syncthreads();
        s[tid] += a;
        __syncthreads();
    }
    ghist[j * 256 + tid] = bbase[j] + s[tid] - v;
}

__global__ void scatter_kernel(const int* __restrict__ h, const int* __restrict__ t,
                               const int* __restrict__ ghist, unsigned* __restrict__ stg,
                               int E, int EPB, int NB) {
    __shared__ int cur[1024];
    int b = blockIdx.x, tid = threadIdx.x;
    for (int j = tid; j < NB; j += 256) cur[j] = ghist[j * gridDim.x + b];
    __syncthreads();
    int s = b * EPB, e = min(s + EPB, E);
    for (int k = s + tid; k < e; k += 256) {
        unsigned hh = (unsigned)h[k];
        int pos = atomicAdd(&cur[hh >> 8], 1);
        stg[pos] = ((hh & 255u) << 18) | (unsigned)t[k];
    }
}

__global__ void finalize_kernel(const unsigned* __restrict__ stg, const int* __restrict__ bbase,
                                int* __restrict__ off, int* __restrict__ csr_t, int N, int E) {
    __shared__ int cnt[256];
    __shared__ int scn[256];
    int b = blockIdx.x, tid = threadIdx.x;
    int ebeg = bbase[b], eend = bbase[b + 1];
    cnt[tid] = 0;
    __syncthreads();
    for (int k = ebeg + tid; k < eend; k += 256)
        atomicAdd(&cnt[(stg[k] >> 18) & 255u], 1);
    __syncthreads();
    int v = cnt[tid];
    scn[tid] = v;
    __syncthreads();
    for (int o = 1; o < 256; o <<= 1) {
        int a = (tid >= o) ? scn[tid - o] : 0;
        __syncthreads();
        scn[tid] += a;
        __syncthreads();
    }
    int excl = scn[tid] - v;
    int gn = (b << 8) + tid;
    if (gn < N) off[gn] = ebeg + excl;
    if (b == 0 && tid == 0) off[N] = E;
    __syncthreads();
    cnt[tid] = excl;   // reuse as cursor
    __syncthreads();
    for (int k = ebeg + tid; k < eend; k += 256) {
        unsigned en = stg[k];
        int slot = atomicAdd(&cnt[(en >> 18) & 255u], 1);
        csr_t[ebeg + slot] = (int)(en & 0x3FFFFu);
    }
}

// bootstrap: A=1 uniform -> prob=0.25, rowsum=deg/4, dcol=2/sqrt(deg).
// prob*dcol is what iteration 0 consumes -> store 0.25*2/sqrt(deg) = 0.5/sqrt(deg).
__global__ void dcol0_kernel(const int* __restrict__ off, float* __restrict__ dcol, int N) {
    int n = blockIdx.x * blockDim.x + threadIdx.x;
    if (n >= N) return;
    float v = 0.5f * rsqrtf((float)(off[n + 1] - off[n]));
    *(float4*)(dcol + (size_t)n * 4) = make_float4(v, v, v, v);
}

// ============ per-layer: xs = bf16(x); tailt = bf16(tanh(x/||x_f||))
__global__ void prep_kernel(const float* __restrict__ x, u16* __restrict__ xs,
                            u16* __restrict__ tailt, int total) {
    int i = blockIdx.x * blockDim.x + threadIdx.x;
    if (i >= total) return;
    float v = x[i];
    xs[i] = f2bf(v);
    float s = v * v;
#pragma unroll
    for (int o = 8; o >= 1; o >>= 1) s += __shfl_xor(s, o);
    float nr = fmaxf(sqrtf(s), 1e-12f);
    tailt[i] = f2bf(ptanh5(v * __builtin_amdgcn_rcpf(nr)));
}

// ============ fused message + routing + next-iteration softmax/dcol
// One 64-lane wave per node. lane l: g=l>>4 (edge slot), m=l&15 (col quad), f=m>>2.
// loop1: acc[j] = sum_k prob[k][f]*dcol_in[t_k][f]*xs[t_k][j]
// head = acc/||acc_f|| (dcol[n] scale-invariant).  WOUT: out[n]=dcol_in[n]*acc.
// loop2 (ROUTE): newA = A + dot16(head, tailt[t]); softmax over f (no max-sub,
// |A|<=49 analytically) -> prob_next; rowsum -> dcol_out[n] = rsqrt(sum).
template <bool UNI, bool WOUT, bool ROUTE>
__global__ void message_kernel(const int* __restrict__ off, const int* __restrict__ csr_t,
                               float* __restrict__ Acsr, float* __restrict__ prob,
                               const u16* __restrict__ xs, const u16* __restrict__ tailt,
                               const float* __restrict__ dcol_in, float* __restrict__ dcol_out,
                               float* __restrict__ out, int N) {
    int gid = blockIdx.x * blockDim.x + threadIdx.x;
    int n = gid >> 6;
    if (n >= N) return;
    int l = gid & 63;
    int g = l >> 4;
    int m = l & 15;
    int f = m >> 2;
    int s = off[n], e = off[n + 1];

    float a0 = 0.f, a1 = 0.f, a2 = 0.f, a3 = 0.f;

#pragma unroll 2
    for (int k = s; k < e; k += 8) {
        int e1 = k + g, e2 = e1 + 4;
        bool v1 = e1 < e, v2 = e2 < e;
        int c1 = v1 ? e1 : s;
        int c2 = v2 ? e2 : s;
        int t1 = csr_t[c1], t2 = csr_t[c2];
        float p1, p2;
        if (UNI) {
            p1 = dcol_in[t1 * 4 + f];                              // prob folded in
            p2 = dcol_in[t2 * 4 + f];
        } else {
            p1 = prob[(size_t)c1 * 4 + f] * dcol_in[t1 * 4 + f];
            p2 = prob[(size_t)c2 * 4 + f] * dcol_in[t2 * 4 + f];
        }
        p1 = v1 ? p1 : 0.f;
        p2 = v2 ? p2 : 0.f;
        const uint2 x1 = *(const uint2*)(xs + ((size_t)t1 << 6) + (m << 2));
        const uint2 x2 = *(const uint2*)(xs + ((size_t)t2 << 6) + (m << 2));
        a0 += p1 * lo16(x1.x) + p2 * lo16(x2.x);
        a1 += p1 * hi16(x1.x) + p2 * hi16(x2.x);
        a2 += p1 * lo16(x1.y) + p2 * lo16(x2.y);
        a3 += p1 * hi16(x1.y) + p2 * hi16(x2.y);
    }

    // combine the 4 edge slots
    a0 += __shfl_xor(a0, 16); a1 += __shfl_xor(a1, 16);
    a2 += __shfl_xor(a2, 16); a3 += __shfl_xor(a3, 16);
    a0 += __shfl_xor(a0, 32); a1 += __shfl_xor(a1, 32);
    a2 += __shfl_xor(a2, 32); a3 += __shfl_xor(a3, 32);

    if (WOUT) {
        float dn = dcol_in[n * 4 + f];
        if (l < 16) {
            *(float4*)(out + ((size_t)n << 6) + (m << 2)) =
                make_float4(a0 * dn, a1 * dn, a2 * dn, a3 * dn);
        }
    }
    if (!ROUTE) return;

    // head = l2norm per factor (scale-invariant: dcol[n] factor drops out)
    float ss = a0 * a0 + a1 * a1 + a2 * a2 + a3 * a3;
    ss += __shfl_xor(ss, 1);
    ss += __shfl_xor(ss, 2);
    float inv = 1.0f / fmaxf(sqrtf(ss), 1e-12f);
    float h0 = a0 * inv, h1 = a1 * inv, h2 = a2 * inv, h3 = a3 * inv;

    float rowsumf = 0.f;

#pragma unroll 2
    for (int k = s; k < e; k += 8) {
        int e1 = k + g, e2 = e1 + 4;
        bool v1 = e1 < e, v2 = e2 < e;
        int c1 = v1 ? e1 : s;
        int c2 = v2 ? e2 : s;
        int t1 = csr_t[c1], t2 = csr_t[c2];
        const uint2 tv1 = *(const uint2*)(tailt + ((size_t)t1 << 6) + (m << 2));
        const uint2 tv2 = *(const uint2*)(tailt + ((size_t)t2 << 6) + (m << 2));
        float d1 = h0 * lo16(tv1.x) + h1 * hi16(tv1.x)
                 + h2 * lo16(tv1.y) + h3 * hi16(tv1.y);
        float d2 = h0 * lo16(tv2.x) + h1 * hi16(tv2.x)
                 + h2 * lo16(tv2.y) + h3 * hi16(tv2.y);
        d1 += __shfl_xor(d1, 1); d1 += __shfl_xor(d1, 2);
        d2 += __shfl_xor(d2, 1); d2 += __shfl_xor(d2, 2);
        float na1 = Acsr[(size_t)c1 * 4 + f] + d1;
        float na2 = Acsr[(size_t)c2 * 4 + f] + d2;
        // softmax over the 4 factors (lane bits 2..3 of m), no max-sub: |na|<=49
        float ex1 = __expf(na1);
        float ex2 = __expf(na2);
        float se1 = ex1 + __shfl_xor(ex1, 4); se1 += __shfl_xor(se1, 8);
        float se2 = ex2 + __shfl_xor(ex2, 4); se2 += __shfl_xor(se2, 8);
        float p1 = ex1 * __builtin_amdgcn_rcpf(se1);
        float p2 = ex2 * __builtin_amdgcn_rcpf(se2);
        if ((m & 3) == 0) {
            if (v1) { Acsr[(size_t)e1 * 4 + f] = na1; prob[(size_t)e1 * 4 + f] = p1; }
            if (v2) { Acsr[(size_t)e2 * 4 + f] = na2; prob[(size_t)e2 * 4 + f] = p2; }
        }
        rowsumf += (v1 ? p1 : 0.f) + (v2 ? p2 : 0.f);
    }

    rowsumf += __shfl_xor(rowsumf, 16);
    rowsumf += __shfl_xor(rowsumf, 32);
    if (l < 16 && (m & 3) == 0) dcol_out[n * 4 + f] = rsqrtf(rowsumf);
}

// acc += v; if final, acc = (acc + v) / 3
__global__ void acc_kernel(float* __restrict__ acc, const float* __restrict__ v, int n, int final_) {
    int i = blockIdx.x * blockDim.x + threadIdx.x;
    if (i >= n) return;
    float r = acc[i] + v[i];
    acc[i] = final_ ? r * (1.0f / 3.0f) : r;
}

extern "C" void kernel_launch(void* const* d_in, const int* in_sizes, int n_in,
                              void* d_out, int out_size, void* d_ws, size_t ws_size,
                              hipStream_t stream) {
    const float* user_emb = (const float*)d_in[0];
    const float* item_emb = (const float*)d_in[1];
    const int* h = (const int*)d_in[2];
    const int* t = (const int*)d_in[3];

    const int nu_elems = in_sizes[0];
    const int ni_elems = in_sizes[1];
    const int total = nu_elems + ni_elems;   // N * 64
    const int N = total / DEMB;
    const int E = in_sizes[2];
    const int NB = (N + 255) >> 8;           // buckets (<= 1024)
    const int NBLK = 256;
    const int EPB = (E + NBLK - 1) / NBLK;

    float* acc = (float*)d_out;

    // ---- workspace layout ----
    float* x     = (float*)d_ws;                    // total f32
    float* out   = x + (size_t)total;               // total f32
    float* Acsr  = out + (size_t)total;             // 4E f32
    float* prob  = Acsr + (size_t)4 * E;            // 4E f32 (first E aliased as stg)
    float* dcolA = prob + (size_t)4 * E;            // 4N f32
    float* dcolB = dcolA + (size_t)4 * N;           // 4N f32
    u16* xs      = (u16*)(dcolB + (size_t)4 * N);   // total u16
    u16* tailt   = xs + (size_t)total;              // total u16
    int* ghist   = (int*)(tailt + (size_t)total);   // NB*256
    int* btot    = ghist + (size_t)NB * 256;        // NB
    int* bbase   = btot + ((NB + 3) & ~3);          // NB+1
    int* off     = bbase + ((NB + 5) & ~3);         // N+1
    int* csr_t   = off + ((N + 4) & ~3);            // E
    unsigned* stg = (unsigned*)prob;                // E (time-disjoint with prob)

    const int BLK = 256;
    const int gE = (E + BLK - 1) / BLK;
    const int gTot = (total + BLK - 1) / BLK;
    const int gN = (N + BLK - 1) / BLK;
    const int gNodeWave = (N * 64 + BLK - 1) / BLK;

    concat_copy_kernel<<<gTot, BLK, 0, stream>>>(user_emb, item_emb, x, acc, nu_elems, total);

    // CSR build v3 (deterministic, no contended global atomics)
    hist_kernel<<<NBLK, 256, 0, stream>>>(h, ghist, E, EPB, NB);
    btot_kernel<<<NB, 256, 0, stream>>>(ghist, btot);
    bscan_kernel<<<1, 1024, 0, stream>>>(btot, bbase, NB, E);
    bofs_kernel<<<NB, 256, 0, stream>>>(ghist, bbase);
    scatter_kernel<<<NBLK, 256, 0, stream>>>(h, t, ghist, stg, E, EPB, NB);
    finalize_kernel<<<NB, 256, 0, stream>>>(stg, bbase, off, csr_t, N, E);

    init_A_kernel<<<gE, BLK, 0, stream>>>((float4*)Acsr, E);
    dcol0_kernel<<<gN, BLK, 0, stream>>>(off, dcolA, N);

    // ---- layer 0 (x fixed; out written only on layer-final iteration) ----
    prep_kernel<<<gTot, BLK, 0, stream>>>(x, xs, tailt, total);
    message_kernel<true, false, true><<<gNodeWave, BLK, 0, stream>>>(
        off, csr_t, Acsr, prob, xs, tailt, dcolA, dcolB, out, N);
    message_kernel<false, true, true><<<gNodeWave, BLK, 0, stream>>>(
        off, csr_t, Acsr, prob, xs, tailt, dcolB, dcolA, out, N);
    acc_kernel<<<gTot, BLK, 0, stream>>>(acc, out, total, 0);

    // ---- layer 1 (input = out; result into x buffer) ----
    prep_kernel<<<gTot, BLK, 0, stream>>>(out, xs, tailt, total);
    message_kernel<false, false, true><<<gNodeWave, BLK, 0, stream>>>(
        off, csr_t, Acsr, prob, xs, tailt, dcolA, dcolB, x, N);
    message_kernel<false, true, false><<<gNodeWave, BLK, 0, stream>>>(
        off, csr_t, Acsr, prob, xs, tailt, dcolB, dcolA, x, N);
    acc_kernel<<<gTot, BLK, 0, stream>>>(acc, x, total, 1);
}